// Round 5
// baseline (125.549 us; speedup 1.0000x reference)
//
#include <hip/hip_runtime.h>

#define LOG2E 1.4426950408889634f

// Problem constants
constexpr int Bb = 4, LQ = 512, LK = 512, QS = 512, H = 256, DV = 512;
constexpr int M = 2048;   // B*LQ

// Workspace byte offsets
constexpr size_t OFF_EQT = 0;            // [256][2048] f32 (2 MiB) exp2-domain q proj (pre-scaled 2^-13)
constexpr size_t OFF_EKT = 2u << 20;     // [256][2048] f32 (2 MiB)
constexpr size_t OFF_PQ  = 4u << 20;     // [4][512][512] bf16 (2 MiB) P numerators
constexpr size_t OFF_ROW = 6u << 20;     // [8][2048] f32 rowsum partials
constexpr size_t OFF_VT  = 8u << 20;     // [4][512][512] bf16 V^T ([b][n][k]) (2 MiB)

using bf16x8 = __attribute__((ext_vector_type(8))) short;
using f32x4v = __attribute__((ext_vector_type(4))) float;

__device__ inline unsigned short f2bf(float x) {
    unsigned int u = __float_as_uint(x);
    u += 0x7FFFu + ((u >> 16) & 1u);      // round-to-nearest-even
    return (unsigned short)(u >> 16);
}
// HW packed f32->bf16 (RNE, matches f2bf bit-for-bit on finite inputs).
__device__ inline unsigned int pk2(float lo, float hi) {
    unsigned int r;
    asm("v_cvt_pk_bf16_f32 %0, %1, %2" : "=v"(r) : "v"(lo), "v"(hi));
    return r;
}

// ---------------------------------------------------------------------------
// Kernel A (R19): proj (z=0,1) + vconv (z=2) MERGED into one launch.
// vconv is independent of proj; same-stream ordering previously serialized
// it.  z=2 uses 128 blocks x 512 thr (64k x 128n V tiles).  LDS is a union
// (52 KB) -> 2 blocks/CU co-resident, so z=2 blocks overlap the proj tail.
// proj math unchanged (bit-identical EqT/EkT); staging now issue-early /
// write-late (T14): global loads for kc+1 are in flight during MFMA(kc).
//   EqT[n][m] = exp2( clamp( scale*(A[m]·W[n] + bias[n]), ±13 ) - 13 )  (z=0)
//   EkT[n][m] = exp2( clamp( ..., ±13 ) )                                (z=1)
// ---------------------------------------------------------------------------
__global__ __launch_bounds__(512, 4) void proj_vconv(
    const float* __restrict__ query, const float* __restrict__ key,
    const float* __restrict__ wq, const float* __restrict__ wk,
    const float* __restrict__ bq, const float* __restrict__ bk,
    const float* __restrict__ V, char* __restrict__ ws, float scale)
{
    union Sh {
        struct {
            unsigned short Als[64][136];
            unsigned short Wls[64][136];
            float Ot[64][68];
        } p;
        unsigned short T[128][72];
    };
    __shared__ Sh sh;

    const int tid = threadIdx.x;
    const int z = blockIdx.z;

    if (z == 2) {
        // ---- vconv: V -> bf16 V^T [b][n][k].  128 blocks, 64k x 128n tiles.
        unsigned short* VT = (unsigned short*)(ws + OFF_VT);
        const int id = blockIdx.y * 32 + blockIdx.x;   // 0..127
        const int b = id >> 5;                         // 0..3
        const int t32 = id & 31;                       // 8 k-tiles x 4 n-tiles
        const int k0 = (t32 & 7) * 64, n0 = (t32 >> 3) * 128;
        const float* Vb = V + (size_t)b * 512 * 512;
        const int r = tid >> 5, c = (tid & 31) * 4;
#pragma unroll
        for (int it = 0; it < 4; ++it) {
            int kr = r + it * 16;
            float4 v = *(const float4*)(Vb + (size_t)(k0 + kr) * 512 + n0 + c);
            sh.T[c + 0][kr] = f2bf(v.x);
            sh.T[c + 1][kr] = f2bf(v.y);
            sh.T[c + 2][kr] = f2bf(v.z);
            sh.T[c + 3][kr] = f2bf(v.w);
        }
        __syncthreads();
        const int rowO = tid >> 2, colO = (tid & 3) * 16;
        uint4 o0 = *(const uint4*)&sh.T[rowO][colO];
        uint4 o1 = *(const uint4*)&sh.T[rowO][colO + 8];
        unsigned short* dst = VT + ((size_t)b * 512 + n0 + rowO) * 512 + k0 + colO;
        *(uint4*)(dst)     = o0;
        *(uint4*)(dst + 8) = o1;
        return;
    }

    // ---- proj path
    const float* A    = z ? key : query;   // [2048][512]
    const float* W    = z ? wk : wq;       // [256][512]
    const float* bias = z ? bk : bq;
    float* out = (float*)(ws + (z ? OFF_EKT : OFF_EQT));   // [256][2048]
    const float off = z ? 0.0f : 13.0f;

    const int mb = blockIdx.x * 64, nb = blockIdx.y * 64;
    const int wid = tid >> 6, lane = tid & 63;
    const int ml = lane & 15, quad = lane >> 4;
    const int ms = wid & 3, nh = wid >> 2;    // m-subtile, n-half

    f32x4v acc0 = {0, 0, 0, 0}, acc1 = {0, 0, 0, 0};

    // register-staged prefetch (issue-early / write-late)
    float4 ra0[2], ra1[2], rw0[2], rw1[2];
    const int row0 = tid >> 4, c80 = (tid & 15) * 8;          // unit 0
    const int row1 = (tid + 512) >> 4, c81 = c80;             // unit 1 (tid+512)
#define PROJ_LOAD(KC)                                                          \
    {                                                                          \
        ra0[0] = *(const float4*)(A + (size_t)(mb + row0) * 512 + (KC) + c80); \
        ra1[0] = *(const float4*)(A + (size_t)(mb + row0) * 512 + (KC) + c80 + 4); \
        rw0[0] = *(const float4*)(W + (size_t)(nb + row0) * 512 + (KC) + c80); \
        rw1[0] = *(const float4*)(W + (size_t)(nb + row0) * 512 + (KC) + c80 + 4); \
        ra0[1] = *(const float4*)(A + (size_t)(mb + row1) * 512 + (KC) + c81); \
        ra1[1] = *(const float4*)(A + (size_t)(mb + row1) * 512 + (KC) + c81 + 4); \
        rw0[1] = *(const float4*)(W + (size_t)(nb + row1) * 512 + (KC) + c81); \
        rw1[1] = *(const float4*)(W + (size_t)(nb + row1) * 512 + (KC) + c81 + 4); \
    }

    PROJ_LOAD(0);
    for (int kc = 0; kc < QS; kc += 128) {
        // write staged tile kc to LDS
#pragma unroll
        for (int it = 0; it < 2; ++it) {
            int row = it ? row1 : row0;
            uint4 pa = { pk2(ra0[it].x, ra0[it].y), pk2(ra0[it].z, ra0[it].w),
                         pk2(ra1[it].x, ra1[it].y), pk2(ra1[it].z, ra1[it].w) };
            *(uint4*)&sh.p.Als[row][c80] = pa;
            uint4 pw = { pk2(rw0[it].x, rw0[it].y), pk2(rw0[it].z, rw0[it].w),
                         pk2(rw1[it].x, rw1[it].y), pk2(rw1[it].z, rw1[it].w) };
            *(uint4*)&sh.p.Wls[row][c80] = pw;
        }
        __syncthreads();
        if (kc < QS - 128) PROJ_LOAD(kc + 128);   // in flight during MFMA
#pragma unroll
        for (int s = 0; s < 4; ++s) {
            int k = s * 32 + quad * 8;
            bf16x8 af = *(const bf16x8*)&sh.p.Als[ms * 16 + ml][k];
            bf16x8 b0 = *(const bf16x8*)&sh.p.Wls[(nh * 2 + 0) * 16 + ml][k];
            bf16x8 b1 = *(const bf16x8*)&sh.p.Wls[(nh * 2 + 1) * 16 + ml][k];
            acc0 = __builtin_amdgcn_mfma_f32_16x16x32_bf16(af, b0, acc0, 0, 0, 0);
            acc1 = __builtin_amdgcn_mfma_f32_16x16x32_bf16(af, b1, acc1, 0, 0, 0);
        }
        __syncthreads();   // protect next iteration's ds_write
    }
#undef PROJ_LOAD

#pragma unroll
    for (int r = 0; r < 4; ++r) {
        sh.p.Ot[(nh * 2 + 0) * 16 + ml][ms * 16 + quad * 4 + r] = acc0[r];
        sh.p.Ot[(nh * 2 + 1) * 16 + ml][ms * 16 + quad * 4 + r] = acc1[r];
    }
    __syncthreads();
    {
        int r0 = tid >> 3;            // n-local 0..63
        int c0 = (tid & 7) * 8;       // m-local base
        float bs = bias[nb + r0];
#pragma unroll
        for (int g = 0; g < 2; ++g) {
            float4 v = *(const float4*)&sh.p.Ot[r0][c0 + g * 4];
            float4 o;
            o.x = __builtin_amdgcn_exp2f(fminf(fmaxf(scale * (v.x + bs), -13.f), 13.f) - off);
            o.y = __builtin_amdgcn_exp2f(fminf(fmaxf(scale * (v.y + bs), -13.f), 13.f) - off);
            o.z = __builtin_amdgcn_exp2f(fminf(fmaxf(scale * (v.z + bs), -13.f), 13.f) - off);
            o.w = __builtin_amdgcn_exp2f(fminf(fmaxf(scale * (v.w + bs), -13.f), 13.f) - off);
            *(float4*)(out + (size_t)(nb + r0) * 2048 + mb + c0 + g * 4) = o;
        }
    }
}

// ---------------------------------------------------------------------------
// Kernel B (R19): scores -> P = exp2(-acc) bf16 + per-ktile row partials.
//   acc(q,k) = sum_h Wv2[h]/(1 + Eq[h][q]*Ek[h][k])   (8-way rcp pairing,
//   s=2^-13 pre-folded into Eq and Wv2 -> exact ratio, no overflow)
// Math identical to R16.  NEW: double-buffered Qs/Ks with register
// prefetch -> ONE barrier per h-tile (was 2) and global-load latency
// hidden under the ~2000-cycle compute phase.
// Safety: write to buf[(t+1)&1] at end of iter t cannot race reads of the
// same buffer from iter t-1 — the barrier at top of iter t orders them.
// ---------------------------------------------------------------------------
__global__ __launch_bounds__(512, 4) void score_kernel(
    const float* __restrict__ wvp, char* __restrict__ ws)
{
    const float* EqT = (const float*)(ws + OFF_EQT);   // [256][2048], pre-scaled 2^-13
    const float* EkT = (const float*)(ws + OFF_EKT);
    unsigned short* Pq = (unsigned short*)(ws + OFF_PQ);  // [4][512][512] bf16
    float* rowpart = (float*)(ws + OFF_ROW);              // [8][2048]

    __shared__ float Qs[2][64][32];
    __shared__ float Ks[2][64][64];
    __shared__ float Wv2[H];
    __shared__ float redS[8][32];

    const int b  = blockIdx.z;
    const int qb = blockIdx.x * 32;
    const int kt = blockIdx.y;
    const int kb = kt * 64;
    const int tid = threadIdx.x;
    const int tx = tid & 15;       // q frag: tx*2 + i
    const int ty = tid >> 4;       // k frag: ty*2 + j   (0..31)
    const int w  = tid >> 6;       // 0..7
    const int lane = tid & 63;

    constexpr float S = 0.0001220703125f;   // 2^-13
    if (tid < H) Wv2[tid] = wvp[tid] * (2.0f * LOG2E) * S;   // fold one s into w

    const int mq = b * LQ + qb;
    const int mk = b * LK + kb;
    const int hq = tid >> 3, cq = (tid & 7) * 4;
    const int hk = tid >> 4, ck = (tid & 15) * 4;

    // prologue: tile 0 -> buf 0 (visible after the t=0 barrier)
    float4 pq, pk0, pk1;
    pq  = *(const float4*)(EqT + (size_t)hq * M + mq + cq);
    pk0 = *(const float4*)(EkT + (size_t)hk * M + mk + ck);
    pk1 = *(const float4*)(EkT + (size_t)(hk + 32) * M + mk + ck);
    *(float4*)&Qs[0][hq][cq]      = pq;
    *(float4*)&Ks[0][hk][ck]      = pk0;
    *(float4*)&Ks[0][hk + 32][ck] = pk1;

    float acc[2][2] = {};

    for (int t = 0; t < 4; ++t) {
        __syncthreads();   // buf[t&1] visible; also covers Wv2 on t=0
        if (t < 3) {       // issue next-tile loads; land during compute
            int h0n = (t + 1) * 64;
            pq  = *(const float4*)(EqT + (size_t)(h0n + hq) * M + mq + cq);
            pk0 = *(const float4*)(EkT + (size_t)(h0n + hk) * M + mk + ck);
            pk1 = *(const float4*)(EkT + (size_t)(h0n + hk + 32) * M + mk + ck);
        }
        const int h0 = t * 64;
        const int cb = t & 1;
#pragma unroll 2
        for (int hh = 0; hh < 64; hh += 8) {
            float2 qv[8], kv[8];
#pragma unroll
            for (int u = 0; u < 8; ++u) qv[u] = *(const float2*)&Qs[cb][hh + u][tx * 2];
#pragma unroll
            for (int u = 0; u < 8; ++u) kv[u] = *(const float2*)&Ks[cb][hh + u][ty * 2];
            const float4 wA = *(const float4*)&Wv2[h0 + hh];
            const float4 wB = *(const float4*)&Wv2[h0 + hh + 4];
#pragma unroll
            for (int i = 0; i < 2; ++i)
#pragma unroll
                for (int j = 0; j < 2; ++j) {
                    float t8a[8];
#pragma unroll
                    for (int u = 0; u < 8; ++u)
                        t8a[u] = fmaf(i ? qv[u].y : qv[u].x, j ? kv[u].y : kv[u].x, S);
                    float t12 = t8a[0] * t8a[1], t34 = t8a[2] * t8a[3];
                    float n12 = fmaf(wA.x, t8a[1], wA.y * t8a[0]);
                    float n34 = fmaf(wA.z, t8a[3], wA.w * t8a[2]);
                    float numA = fmaf(n12, t34, n34 * t12);
                    float denA = t12 * t34;
                    float t56 = t8a[4] * t8a[5], t78 = t8a[6] * t8a[7];
                    float m12 = fmaf(wB.x, t8a[5], wB.y * t8a[4]);
                    float m34 = fmaf(wB.z, t8a[7], wB.w * t8a[6]);
                    float numB = fmaf(m12, t78, m34 * t56);
                    float denB = t56 * t78;
                    float NUMv = fmaf(numA, denB, numB * denA);
                    float DENv = denA * denB;
                    acc[i][j] = fmaf(NUMv, __builtin_amdgcn_rcpf(DENv), acc[i][j]);
                }
        }
        if (t < 3) {       // write next tile to the other buffer
            const int nb2 = (t + 1) & 1;
            *(float4*)&Qs[nb2][hq][cq]      = pq;
            *(float4*)&Ks[nb2][hk][ck]      = pk0;
            *(float4*)&Ks[nb2][hk + 32][ck] = pk1;
        }
    }

    // Epilogue: P = exp2(-acc) -> bf16 Pq[b][q][kb+ty*2..+1]; row partials.
    float ps[2];
#pragma unroll
    for (int i = 0; i < 2; ++i) {
        int q = qb + tx * 2 + i;
        float p0 = __builtin_amdgcn_exp2f(-acc[i][0]);
        float p1 = __builtin_amdgcn_exp2f(-acc[i][1]);
        ps[i] = p0 + p1;
        *(unsigned int*)(Pq + ((size_t)(b * 512 + q) * 512 + kb + ty * 2)) = pk2(p0, p1);
    }
#pragma unroll
    for (int i = 0; i < 2; ++i) {
        ps[i] += __shfl_xor(ps[i], 16, 64);
        ps[i] += __shfl_xor(ps[i], 32, 64);
    }
    if (lane < 16) {
#pragma unroll
        for (int i = 0; i < 2; ++i) redS[w][tx * 2 + i] = ps[i];
    }
    __syncthreads();
    if (tid < 32) {
        float s = ((redS[0][tid] + redS[1][tid]) + (redS[2][tid] + redS[3][tid]))
                + ((redS[4][tid] + redS[5][tid]) + (redS[6][tid] + redS[7][tid]));
        rowpart[(size_t)kt * 2048 + b * 512 + qb + tid] = s;
    }
}

// ---------------------------------------------------------------------------
// Kernel C (R19): out = (P @ V) / rowsum via bf16 MFMA.  Math unchanged;
// staging now issue-early / write-late so the global uint4 loads for kc+1
// are in flight during MFMA(kc).
// ---------------------------------------------------------------------------
__global__ __launch_bounds__(512, 2) void av_mfma(
    const char* __restrict__ wsc, float* __restrict__ O)
{
    const unsigned short* Pq = (const unsigned short*)(wsc + OFF_PQ);
    const unsigned short* VT = (const unsigned short*)(wsc + OFF_VT);
    const float* rowpart = (const float*)(wsc + OFF_ROW);

    __shared__ unsigned short Pls[64][136];
    __shared__ unsigned short Vls[64][136];

    const int b = blockIdx.z, qb = blockIdx.x * 64, nb = blockIdx.y * 64;
    const int tid = threadIdx.x;
    const int wid = tid >> 6, lane = tid & 63;
    const int ml = lane & 15, quad = lane >> 4;
    const int ms = wid & 3, nh = wid >> 2;     // m-subtile, nt-half
    const unsigned short* Pb = Pq + (size_t)b * 512 * 512;
    const unsigned short* Vb = VT + (size_t)b * 512 * 512;

    const int row0 = tid >> 4, c80 = (tid & 15) * 8;
    const int row1 = (tid + 512) >> 4;

    uint4 rp[2], rv[2];
#define AV_LOAD(KC)                                                            \
    {                                                                          \
        rp[0] = *(const uint4*)(Pb + (size_t)(qb + row0) * 512 + (KC) + c80);  \
        rv[0] = *(const uint4*)(Vb + (size_t)(nb + row0) * 512 + (KC) + c80);  \
        rp[1] = *(const uint4*)(Pb + (size_t)(qb + row1) * 512 + (KC) + c80);  \
        rv[1] = *(const uint4*)(Vb + (size_t)(nb + row1) * 512 + (KC) + c80);  \
    }

    f32x4v acc[2] = {{0,0,0,0},{0,0,0,0}};

    AV_LOAD(0);
    for (int kc = 0; kc < LK; kc += 128) {
        *(uint4*)&Pls[row0][c80] = rp[0];
        *(uint4*)&Vls[row0][c80] = rv[0];
        *(uint4*)&Pls[row1][c80] = rp[1];
        *(uint4*)&Vls[row1][c80] = rv[1];
        __syncthreads();
        if (kc < LK - 128) AV_LOAD(kc + 128);   // in flight during MFMA
#pragma unroll
        for (int s = 0; s < 4; ++s) {
            int k = s * 32 + quad * 8;
            bf16x8 af = *(const bf16x8*)&Pls[ms * 16 + ml][k];
#pragma unroll
            for (int t = 0; t < 2; ++t) {
                bf16x8 bfr = *(const bf16x8*)&Vls[(nh * 2 + t) * 16 + ml][k];
                acc[t] = __builtin_amdgcn_mfma_f32_16x16x32_bf16(af, bfr, acc[t], 0, 0, 0);
            }
        }
        __syncthreads();   // protect next iteration's ds_write
    }
#undef AV_LOAD

    float rr[4];
#pragma unroll
    for (int r = 0; r < 4; ++r) {
        int q = qb + ms * 16 + quad * 4 + r;
        float rs = 0.f;
#pragma unroll
        for (int t8 = 0; t8 < 8; ++t8) rs += rowpart[(size_t)t8 * 2048 + b * 512 + q];
        rr[r] = 1.0f / rs;
    }
#pragma unroll
    for (int t = 0; t < 2; ++t)
#pragma unroll
        for (int r = 0; r < 4; ++r) {
            int q = qb + ms * 16 + quad * 4 + r;
            O[((size_t)b * 512 + q) * 512 + nb + (nh * 2 + t) * 16 + ml] = acc[t][r] * rr[r];
        }
}

extern "C" void kernel_launch(void* const* d_in, const int* in_sizes, int n_in,
                              void* d_out, int out_size, void* d_ws, size_t ws_size,
                              hipStream_t stream) {
    const float* query = (const float*)d_in[0];
    const float* key   = (const float*)d_in[1];
    const float* value = (const float*)d_in[2];
    const float* wq    = (const float*)d_in[3];
    const float* bq    = (const float*)d_in[4];
    const float* wk    = (const float*)d_in[5];
    const float* bk    = (const float*)d_in[6];
    const float* wv    = (const float*)d_in[7];
    // d_in[8] = bv: row-constant -> softmax-invariant, dropped.
    float* out = (float*)d_out;
    char* ws = (char*)d_ws;

    const float c2 = 2.0f * LOG2E;

    proj_vconv<<<dim3(32, 4, 3), 512, 0, stream>>>(query, key, wq, wk, bq, bk, value, ws, c2);
    score_kernel<<<dim3(16, 8, Bb), 512, 0, stream>>>(wv, ws);
    av_mfma<<<dim3(8, 8, Bb), 512, 0, stream>>>(ws, out);
}

// Round 6
// 118.230 us; speedup vs baseline: 1.0619x; 1.0619x over previous
//
#include <hip/hip_runtime.h>

#define LOG2E 1.4426950408889634f

// Problem constants
constexpr int Bb = 4, LQ = 512, LK = 512, QS = 512, H = 256, DV = 512;
constexpr int M = 2048;   // B*LQ

// Workspace byte offsets
constexpr size_t OFF_EQT = 0;            // [256][2048] f32 (2 MiB) exp2-domain q proj (pre-scaled 2^-13)
constexpr size_t OFF_EKT = 2u << 20;     // [256][2048] f32 (2 MiB)
constexpr size_t OFF_PQ  = 4u << 20;     // [4][512][512] bf16 (2 MiB) P numerators
constexpr size_t OFF_ROW = 6u << 20;     // [8][2048] f32 rowsum partials
constexpr size_t OFF_VT  = 8u << 20;     // [4][512][512] bf16 V^T ([b][n][k]) (2 MiB)

using bf16x8 = __attribute__((ext_vector_type(8))) short;
using f32x4v = __attribute__((ext_vector_type(4))) float;

__device__ inline unsigned short f2bf(float x) {
    unsigned int u = __float_as_uint(x);
    u += 0x7FFFu + ((u >> 16) & 1u);      // round-to-nearest-even
    return (unsigned short)(u >> 16);
}
// HW packed f32->bf16 (RNE, matches f2bf bit-for-bit on finite inputs).
__device__ inline unsigned int pk2(float lo, float hi) {
    unsigned int r;
    asm("v_cvt_pk_bf16_f32 %0, %1, %2" : "=v"(r) : "v"(lo), "v"(hi));
    return r;
}

// ---------------------------------------------------------------------------
// Kernel A (R20): proj (blockIdx.x < 32) + vconv (blockIdx.x >= 32) in ONE
// launch.  R5's union/prefetch/double-buffer REVERTED (regressed) — proj
// body is R4's verbatim (2-barrier loop, compiler-scheduled).  vconv blocks
// are independent work that overlaps proj and removes one launch boundary.
// LDS: 69 KB static (proj 52 + T 18) -> 2 blocks/CU.
//   EqT[n][m] = exp2( clamp( scale*(A[m]·W[n] + bias[n]), ±13 ) - 13 )  (z=0)
//   EkT[n][m] = exp2( clamp( ..., ±13 ) )                                (z=1)
//   VT[b][n][k] = f2bf(V[b][k][n])
// ---------------------------------------------------------------------------
__global__ __launch_bounds__(512) void proj_vconv(
    const float* __restrict__ query, const float* __restrict__ key,
    const float* __restrict__ wq, const float* __restrict__ wk,
    const float* __restrict__ bq, const float* __restrict__ bk,
    const float* __restrict__ V, char* __restrict__ ws, float scale)
{
    __shared__ unsigned short Als[64][136];
    __shared__ unsigned short Wls[64][136];
    __shared__ float Ot[64][68];
    __shared__ unsigned short T[128][72];

    const int tid = threadIdx.x;
    const int z = blockIdx.z;

    if (blockIdx.x >= 32) {
        // ---- vconv: V -> bf16 V^T [b][n][k].  128 blocks, 64k x 128n tiles.
        unsigned short* VT = (unsigned short*)(ws + OFF_VT);
        const int id = (blockIdx.x - 32) + 16 * (blockIdx.y + 4 * z);   // 0..127
        const int b = id >> 5;                         // 0..3
        const int t32 = id & 31;                       // 8 k-tiles x 4 n-tiles
        const int k0 = (t32 & 7) * 64, n0 = (t32 >> 3) * 128;
        const float* Vb = V + (size_t)b * 512 * 512;
        const int r = tid >> 5, c = (tid & 31) * 4;
#pragma unroll
        for (int it = 0; it < 4; ++it) {
            int kr = r + it * 16;
            float4 v = *(const float4*)(Vb + (size_t)(k0 + kr) * 512 + n0 + c);
            T[c + 0][kr] = f2bf(v.x);
            T[c + 1][kr] = f2bf(v.y);
            T[c + 2][kr] = f2bf(v.z);
            T[c + 3][kr] = f2bf(v.w);
        }
        __syncthreads();
        const int rowO = tid >> 2, colO = (tid & 3) * 16;
        uint4 o0 = *(const uint4*)&T[rowO][colO];
        uint4 o1 = *(const uint4*)&T[rowO][colO + 8];
        unsigned short* dst = VT + ((size_t)b * 512 + n0 + rowO) * 512 + k0 + colO;
        *(uint4*)(dst)     = o0;
        *(uint4*)(dst + 8) = o1;
        return;
    }

    // ---- proj path (R4 verbatim)
    const float* A    = z ? key : query;   // [2048][512]
    const float* W    = z ? wk : wq;       // [256][512]
    const float* bias = z ? bk : bq;
    float* out = (float*)(ws + (z ? OFF_EKT : OFF_EQT));   // [256][2048]
    const float off = z ? 0.0f : 13.0f;

    const int mb = blockIdx.x * 64, nb = blockIdx.y * 64;
    const int wid = tid >> 6, lane = tid & 63;
    const int ml = lane & 15, quad = lane >> 4;
    const int ms = wid & 3, nh = wid >> 2;    // m-subtile, n-half

    f32x4v acc0 = {0, 0, 0, 0}, acc1 = {0, 0, 0, 0};

    for (int kc = 0; kc < QS; kc += 128) {
        __syncthreads();
#pragma unroll
        for (int it = 0; it < 2; ++it) {
            int u = tid + it * 512;          // 0..1023 units of 8 elems
            int row = u >> 4, c8 = (u & 15) * 8;
            float4 a0 = *(const float4*)(A + (size_t)(mb + row) * 512 + kc + c8);
            float4 a1 = *(const float4*)(A + (size_t)(mb + row) * 512 + kc + c8 + 4);
            uint4 pa = { pk2(a0.x, a0.y), pk2(a0.z, a0.w), pk2(a1.x, a1.y), pk2(a1.z, a1.w) };
            *(uint4*)&Als[row][c8] = pa;
            float4 w0 = *(const float4*)(W + (size_t)(nb + row) * 512 + kc + c8);
            float4 w1 = *(const float4*)(W + (size_t)(nb + row) * 512 + kc + c8 + 4);
            uint4 pw = { pk2(w0.x, w0.y), pk2(w0.z, w0.w), pk2(w1.x, w1.y), pk2(w1.z, w1.w) };
            *(uint4*)&Wls[row][c8] = pw;
        }
        __syncthreads();
#pragma unroll
        for (int s = 0; s < 4; ++s) {
            int k = s * 32 + quad * 8;
            bf16x8 af = *(const bf16x8*)&Als[ms * 16 + ml][k];
            bf16x8 b0 = *(const bf16x8*)&Wls[(nh * 2 + 0) * 16 + ml][k];
            bf16x8 b1 = *(const bf16x8*)&Wls[(nh * 2 + 1) * 16 + ml][k];
            acc0 = __builtin_amdgcn_mfma_f32_16x16x32_bf16(af, b0, acc0, 0, 0, 0);
            acc1 = __builtin_amdgcn_mfma_f32_16x16x32_bf16(af, b1, acc1, 0, 0, 0);
        }
    }

    __syncthreads();
#pragma unroll
    for (int r = 0; r < 4; ++r) {
        Ot[(nh * 2 + 0) * 16 + ml][ms * 16 + quad * 4 + r] = acc0[r];
        Ot[(nh * 2 + 1) * 16 + ml][ms * 16 + quad * 4 + r] = acc1[r];
    }
    __syncthreads();
    {
        int r0 = tid >> 3;            // n-local 0..63
        int c0 = (tid & 7) * 8;       // m-local base
        float bs = bias[nb + r0];
#pragma unroll
        for (int g = 0; g < 2; ++g) {
            float4 v = *(const float4*)&Ot[r0][c0 + g * 4];
            float4 o;
            o.x = __builtin_amdgcn_exp2f(fminf(fmaxf(scale * (v.x + bs), -13.f), 13.f) - off);
            o.y = __builtin_amdgcn_exp2f(fminf(fmaxf(scale * (v.y + bs), -13.f), 13.f) - off);
            o.z = __builtin_amdgcn_exp2f(fminf(fmaxf(scale * (v.z + bs), -13.f), 13.f) - off);
            o.w = __builtin_amdgcn_exp2f(fminf(fmaxf(scale * (v.w + bs), -13.f), 13.f) - off);
            *(float4*)(out + (size_t)(nb + r0) * 2048 + mb + c0 + g * 4) = o;
        }
    }
}

// ---------------------------------------------------------------------------
// Kernel B: scores -> P = exp2(-acc) bf16 [b][q][k] + per-ktile row partials.
//   acc(q,k) = sum_h Wv2[h]/(1 + Eq[h][q]*Ek[h][k])   (8-way rcp pairing,
//   s=2^-13 pre-folded into Eq and Wv2 -> exact ratio, no overflow)
// (R16/R2 verbatim — R5's double-buffer reverted)
// ---------------------------------------------------------------------------
__global__ __launch_bounds__(512, 4) void score_kernel(
    const float* __restrict__ wvp, char* __restrict__ ws)
{
    const float* EqT = (const float*)(ws + OFF_EQT);   // [256][2048], pre-scaled 2^-13
    const float* EkT = (const float*)(ws + OFF_EKT);
    unsigned short* Pq = (unsigned short*)(ws + OFF_PQ);  // [4][512][512] bf16
    float* rowpart = (float*)(ws + OFF_ROW);              // [8][2048]

    __shared__ float Qs[64][32];
    __shared__ float Ks[64][64];
    __shared__ float Wv2[H];
    __shared__ float redS[8][32];

    const int b  = blockIdx.z;
    const int qb = blockIdx.x * 32;
    const int kt = blockIdx.y;
    const int kb = kt * 64;
    const int tid = threadIdx.x;
    const int tx = tid & 15;       // q frag: tx*2 + i
    const int ty = tid >> 4;       // k frag: ty*2 + j   (0..31)
    const int w  = tid >> 6;       // 0..7
    const int lane = tid & 63;

    constexpr float S = 0.0001220703125f;   // 2^-13
    if (tid < H) Wv2[tid] = wvp[tid] * (2.0f * LOG2E) * S;   // fold one s into w

    const int mq = b * LQ + qb;
    const int mk = b * LK + kb;

    float acc[2][2] = {};

    for (int h0 = 0; h0 < H; h0 += 64) {
        __syncthreads();   // also covers the Wv2 write on the first pass
        {
            int hq = tid >> 3, cq = (tid & 7) * 4;
            *(float4*)&Qs[hq][cq] = *(const float4*)(EqT + (size_t)(h0 + hq) * M + mq + cq);
            int hk = tid >> 4, ck = (tid & 15) * 4;
            *(float4*)&Ks[hk][ck]      = *(const float4*)(EkT + (size_t)(h0 + hk) * M + mk + ck);
            *(float4*)&Ks[hk + 32][ck] = *(const float4*)(EkT + (size_t)(h0 + hk + 32) * M + mk + ck);
        }
        __syncthreads();
#pragma unroll 2
        for (int hh = 0; hh < 64; hh += 8) {
            float2 qv[8], kv[8];
#pragma unroll
            for (int u = 0; u < 8; ++u) qv[u] = *(const float2*)&Qs[hh + u][tx * 2];
#pragma unroll
            for (int u = 0; u < 8; ++u) kv[u] = *(const float2*)&Ks[hh + u][ty * 2];
            const float4 wA = *(const float4*)&Wv2[h0 + hh];
            const float4 wB = *(const float4*)&Wv2[h0 + hh + 4];
#pragma unroll
            for (int i = 0; i < 2; ++i)
#pragma unroll
                for (int j = 0; j < 2; ++j) {
                    float t[8];
#pragma unroll
                    for (int u = 0; u < 8; ++u)
                        t[u] = fmaf(i ? qv[u].y : qv[u].x, j ? kv[u].y : kv[u].x, S);
                    float t12 = t[0] * t[1], t34 = t[2] * t[3];
                    float n12 = fmaf(wA.x, t[1], wA.y * t[0]);
                    float n34 = fmaf(wA.z, t[3], wA.w * t[2]);
                    float numA = fmaf(n12, t34, n34 * t12);
                    float denA = t12 * t34;
                    float t56 = t[4] * t[5], t78 = t[6] * t[7];
                    float m12 = fmaf(wB.x, t[5], wB.y * t[4]);
                    float m34 = fmaf(wB.z, t[7], wB.w * t[6]);
                    float numB = fmaf(m12, t78, m34 * t56);
                    float denB = t56 * t78;
                    float NUMv = fmaf(numA, denB, numB * denA);
                    float DENv = denA * denB;
                    acc[i][j] = fmaf(NUMv, __builtin_amdgcn_rcpf(DENv), acc[i][j]);
                }
        }
    }

    // Epilogue: P = exp2(-acc) -> bf16 Pq[b][q][kb+ty*2..+1]; row partials.
    float ps[2];
#pragma unroll
    for (int i = 0; i < 2; ++i) {
        int q = qb + tx * 2 + i;
        float p0 = __builtin_amdgcn_exp2f(-acc[i][0]);
        float p1 = __builtin_amdgcn_exp2f(-acc[i][1]);
        ps[i] = p0 + p1;
        *(unsigned int*)(Pq + ((size_t)(b * 512 + q) * 512 + kb + ty * 2)) = pk2(p0, p1);
    }
#pragma unroll
    for (int i = 0; i < 2; ++i) {
        ps[i] += __shfl_xor(ps[i], 16, 64);
        ps[i] += __shfl_xor(ps[i], 32, 64);
    }
    if (lane < 16) {
#pragma unroll
        for (int i = 0; i < 2; ++i) redS[w][tx * 2 + i] = ps[i];
    }
    __syncthreads();
    if (tid < 32) {
        float s = ((redS[0][tid] + redS[1][tid]) + (redS[2][tid] + redS[3][tid]))
                + ((redS[4][tid] + redS[5][tid]) + (redS[6][tid] + redS[7][tid]));
        rowpart[(size_t)kt * 2048 + b * 512 + qb + tid] = s;
    }
}

// ---------------------------------------------------------------------------
// Kernel C: out = (P @ V) / rowsum via bf16 MFMA.  (R4 verbatim —
// R5's issue-early/write-late reverted)
// ---------------------------------------------------------------------------
__global__ __launch_bounds__(512, 2) void av_mfma(
    const char* __restrict__ wsc, float* __restrict__ O)
{
    const unsigned short* Pq = (const unsigned short*)(wsc + OFF_PQ);
    const unsigned short* VT = (const unsigned short*)(wsc + OFF_VT);
    const float* rowpart = (const float*)(wsc + OFF_ROW);

    __shared__ unsigned short Pls[64][136];
    __shared__ unsigned short Vls[64][136];

    const int b = blockIdx.z, qb = blockIdx.x * 64, nb = blockIdx.y * 64;
    const int tid = threadIdx.x;
    const int wid = tid >> 6, lane = tid & 63;
    const int ml = lane & 15, quad = lane >> 4;
    const int ms = wid & 3, nh = wid >> 2;     // m-subtile, nt-half
    const unsigned short* Pb = Pq + (size_t)b * 512 * 512;
    const unsigned short* Vb = VT + (size_t)b * 512 * 512;

    f32x4v acc[2] = {{0,0,0,0},{0,0,0,0}};

    for (int kc = 0; kc < LK; kc += 128) {
        __syncthreads();
#pragma unroll
        for (int it = 0; it < 2; ++it) {
            int u = tid + it * 512;
            int row = u >> 4, c8 = (u & 15) * 8;
            *(uint4*)&Pls[row][c8] = *(const uint4*)(Pb + (size_t)(qb + row) * 512 + kc + c8);
            *(uint4*)&Vls[row][c8] = *(const uint4*)(Vb + (size_t)(nb + row) * 512 + kc + c8);
        }
        __syncthreads();
#pragma unroll
        for (int s = 0; s < 4; ++s) {
            int k = s * 32 + quad * 8;
            bf16x8 af = *(const bf16x8*)&Pls[ms * 16 + ml][k];
#pragma unroll
            for (int t = 0; t < 2; ++t) {
                bf16x8 bfr = *(const bf16x8*)&Vls[(nh * 2 + t) * 16 + ml][k];
                acc[t] = __builtin_amdgcn_mfma_f32_16x16x32_bf16(af, bfr, acc[t], 0, 0, 0);
            }
        }
    }

    float rr[4];
#pragma unroll
    for (int r = 0; r < 4; ++r) {
        int q = qb + ms * 16 + quad * 4 + r;
        float rs = 0.f;
#pragma unroll
        for (int t8 = 0; t8 < 8; ++t8) rs += rowpart[(size_t)t8 * 2048 + b * 512 + q];
        rr[r] = 1.0f / rs;
    }
#pragma unroll
    for (int t = 0; t < 2; ++t)
#pragma unroll
        for (int r = 0; r < 4; ++r) {
            int q = qb + ms * 16 + quad * 4 + r;
            O[((size_t)b * 512 + q) * 512 + nb + (nh * 2 + t) * 16 + ml] = acc[t][r] * rr[r];
        }
}

extern "C" void kernel_launch(void* const* d_in, const int* in_sizes, int n_in,
                              void* d_out, int out_size, void* d_ws, size_t ws_size,
                              hipStream_t stream) {
    const float* query = (const float*)d_in[0];
    const float* key   = (const float*)d_in[1];
    const float* value = (const float*)d_in[2];
    const float* wq    = (const float*)d_in[3];
    const float* bq    = (const float*)d_in[4];
    const float* wk    = (const float*)d_in[5];
    const float* bk    = (const float*)d_in[6];
    const float* wv    = (const float*)d_in[7];
    // d_in[8] = bv: row-constant -> softmax-invariant, dropped.
    float* out = (float*)d_out;
    char* ws = (char*)d_ws;

    const float c2 = 2.0f * LOG2E;

    proj_vconv<<<dim3(48, 4, 2), 512, 0, stream>>>(query, key, wq, wk, bq, bk, value, ws, c2);
    score_kernel<<<dim3(16, 8, Bb), 512, 0, stream>>>(wv, ws);
    av_mfma<<<dim3(8, 8, Bb), 512, 0, stream>>>(ws, out);
}